// Round 1
// baseline (1364.136 us; speedup 1.0000x reference)
//
#include <hip/hip_runtime.h>
#include <math.h>

// Problem constants
#define B_SZ 64
#define N_PTS 2048
#define KGEMM 98304          // N_PTS * 48
#define NOUT 1000
#define NPAD 1024
#define NSPLIT 48
#define KB 2048              // K per split (KB * NSPLIT == KGEMM)

typedef __attribute__((ext_vector_type(8))) unsigned short ushort8;
typedef __attribute__((ext_vector_type(8))) __bf16 bf16x8;
typedef __attribute__((ext_vector_type(4))) float floatx4;

// fp32 -> bf16 round-to-nearest-even (values are finite; no NaN handling needed)
static __device__ __forceinline__ unsigned short f2bf(float x) {
    unsigned int u = __float_as_uint(x);
    u += 0x7FFFu + ((u >> 16) & 1u);
    return (unsigned short)(u >> 16);
}

static __device__ __forceinline__ bf16x8 lds_bf8(const unsigned short* p) {
    return __builtin_bit_cast(bf16x8, *(const ushort8*)p);
}

// ---------------------------------------------------------------------------
// Kernel 1: topview 64x64 -> 4x4 bilinear resize (fixed taps: rows/cols
// {7,23,39,55} with weight 0.5 exactly) + 48x4096 matmul + sigmoid + scale.
// One block per batch image. Output xy[b][o] for o = 2n+k (x at even, y odd).
// ---------------------------------------------------------------------------
__global__ __launch_bounds__(256) void k_coords(const float* __restrict__ tv,
                                                const float* __restrict__ w1,
                                                const float* __restrict__ b1,
                                                float* __restrict__ xy) {
    __shared__ float tvs[48];
    const int b = blockIdx.x;
    const int t = threadIdx.x;
    if (t < 48) {
        const int ch = t >> 4, ij = t & 15, i = ij >> 2, j = ij & 3;
        const float* p = tv + (size_t)((b * 3 + ch) << 12) + (7 + 16 * i) * 64 + (7 + 16 * j);
        tvs[t] = 0.25f * (p[0] + p[1] + p[64] + p[65]);
    }
    __syncthreads();
    for (int s = 0; s < 16; ++s) {
        const int o = (s << 8) + t;         // 0..4095, coalesced w1 access
        float acc = b1[o];
        #pragma unroll
        for (int d = 0; d < 48; ++d)
            acc += tvs[d] * w1[d * 4096 + o];
        const float sg = 1.f / (1.f + __expf(-acc));
        // xs = coord*(H-1-PATCH) + PATCH/2 = coord*1019 + 2  (H == W == 1024)
        xy[(b << 12) + o] = sg * 1019.f + 2.f;
    }
}

// ---------------------------------------------------------------------------
// Kernel 2: bilinear 4x4x3 patch gather -> A matrix (bf16, row-major [64][98304]).
// One thread per (b, n, i, j); computes 3 channels.
// rows use cx/fx, cols use cy/fy (matches reference _crop_patch).
// ---------------------------------------------------------------------------
__global__ __launch_bounds__(256) void k_patch(const float* __restrict__ img,
                                               const float* __restrict__ xy,
                                               unsigned short* __restrict__ A) {
    const int idx = blockIdx.x * 256 + threadIdx.x;       // 2^21 total
    const int j = idx & 3;
    const int i = (idx >> 2) & 3;
    const int n = (idx >> 4) & 2047;
    const int b = idx >> 15;

    const float cx = xy[(b << 12) + 2 * n];
    const float cy = xy[(b << 12) + 2 * n + 1];
    const float x0f = floorf(cx), y0f = floorf(cy);
    const float fx = cx - x0f, fy = cy - y0f;
    const int x0 = (int)x0f, y0 = (int)y0f;
    const int r = x0 + i - 2;     // in [0, 1021]
    const int c = y0 + j - 2;     // +1 and +3072 offsets stay in bounds

    const float* p = img + (size_t)((b * 1024 + r) * 1024 + c) * 3;
    const float w00 = (1.f - fx) * (1.f - fy);
    const float w01 = (1.f - fx) * fy;
    const float w10 = fx * (1.f - fy);
    const float w11 = fx * fy;

    unsigned short* out = A + (size_t)b * KGEMM + n * 48 + i * 12 + j * 3;
    #pragma unroll
    for (int ch = 0; ch < 3; ++ch) {
        const float v = p[ch] * w00 + p[ch + 3] * w01 + p[ch + 3072] * w10 + p[ch + 3075] * w11;
        out[ch] = f2bf(v);
    }
}

// ---------------------------------------------------------------------------
// Kernel 3: split-K GEMM  part[split] += A[64, Kslice] * W[Kslice, 64-col tile]
// grid (16 n-tiles, 48 k-splits), 256 threads = 4 waves.
// Wave w owns 16 output cols [tile*64 + 16w, +16); 4 MFMA m-subtiles cover M=64.
// W (fp32) converted to bf16 on the fly. LDS stride 40 shorts (=80 B) to keep
// bank aliasing at the free 2-way level.
// MFMA 16x16x32 bf16 layouts (m89/m91-verified): A[m=lane&15][k=(lane>>4)*8+j],
// B[k][n=lane&15], D row=(lane>>4)*4+reg, col=lane&15.
// ---------------------------------------------------------------------------
__global__ __launch_bounds__(256) void k_gemm(const unsigned short* __restrict__ A,
                                              const float* __restrict__ W,
                                              float* __restrict__ part) {
    __shared__ unsigned short As[64 * 40];
    __shared__ unsigned short Bs[64 * 40];
    const int t = threadIdx.x;
    const int lane = t & 63;
    const int wv = t >> 6;              // wave id 0..3
    const int tile_n = blockIdx.x;      // 0..15
    const int split = blockIdx.y;       // 0..47
    const int kbase = split * KB;

    const int q = lane >> 4;            // k-quad
    const int lm = lane & 15;

    // A staging: thread -> (row, 16B segment)
    const int arow = t >> 2;            // 0..63
    const int aseg = t & 3;             // 0..3
    // B staging: thread -> (column, k-octet = wave id)
    const int bc = t & 63;
    const int n_glob = tile_n * 64 + bc;
    const bool bok = n_glob < NOUT;

    floatx4 acc0 = {0.f, 0.f, 0.f, 0.f};
    floatx4 acc1 = {0.f, 0.f, 0.f, 0.f};
    floatx4 acc2 = {0.f, 0.f, 0.f, 0.f};
    floatx4 acc3 = {0.f, 0.f, 0.f, 0.f};

    for (int s = 0; s < KB / 32; ++s) {
        const int k0 = kbase + s * 32;
        __syncthreads();
        // stage A tile 64x32 bf16 (16 B per thread)
        *(uint4*)&As[arow * 40 + aseg * 8] =
            *(const uint4*)(A + (size_t)arow * KGEMM + k0 + aseg * 8);
        // stage B tile 32x64, transposed to Bs[n][k], fp32 -> bf16
        {
            const int kk = k0 + wv * 8;
            union { unsigned short us[8]; uint4 v; } pk;
            #pragma unroll
            for (int jj = 0; jj < 8; ++jj) {
                const float v = bok ? W[(size_t)(kk + jj) * NOUT + n_glob] : 0.f;
                pk.us[jj] = f2bf(v);
            }
            *(uint4*)&Bs[bc * 40 + wv * 8] = pk.v;
        }
        __syncthreads();

        const bf16x8 bf = lds_bf8(&Bs[(wv * 16 + lm) * 40 + q * 8]);
        const bf16x8 a0 = lds_bf8(&As[(0 + lm) * 40 + q * 8]);
        const bf16x8 a1 = lds_bf8(&As[(16 + lm) * 40 + q * 8]);
        const bf16x8 a2 = lds_bf8(&As[(32 + lm) * 40 + q * 8]);
        const bf16x8 a3 = lds_bf8(&As[(48 + lm) * 40 + q * 8]);
        acc0 = __builtin_amdgcn_mfma_f32_16x16x32_bf16(a0, bf, acc0, 0, 0, 0);
        acc1 = __builtin_amdgcn_mfma_f32_16x16x32_bf16(a1, bf, acc1, 0, 0, 0);
        acc2 = __builtin_amdgcn_mfma_f32_16x16x32_bf16(a2, bf, acc2, 0, 0, 0);
        acc3 = __builtin_amdgcn_mfma_f32_16x16x32_bf16(a3, bf, acc3, 0, 0, 0);
    }

    // epilogue: write 64x64 fp32 tile into partial buffer [split][64][1024]
    float* pb = part + (size_t)split * (64 * NPAD) + tile_n * 64 + wv * 16 + lm;
    #pragma unroll
    for (int r = 0; r < 4; ++r) {
        pb[(0  + q * 4 + r) * NPAD] = acc0[r];
        pb[(16 + q * 4 + r) * NPAD] = acc1[r];
        pb[(32 + q * 4 + r) * NPAD] = acc2[r];
        pb[(48 + q * 4 + r) * NPAD] = acc3[r];
    }
}

// ---------------------------------------------------------------------------
// Kernel 4: reduce 48 partials + bias -> out[64][1000]
// ---------------------------------------------------------------------------
__global__ __launch_bounds__(256) void k_reduce(const float* __restrict__ part,
                                                const float* __restrict__ b2,
                                                float* __restrict__ out) {
    const int idx = blockIdx.x * 256 + threadIdx.x;  // 0..65535 == m*1024 + o
    const int m = idx >> 10;
    const int o = idx & 1023;
    if (o >= NOUT) return;
    float s = b2[o];
    #pragma unroll 8
    for (int sp = 0; sp < NSPLIT; ++sp)
        s += part[(size_t)sp * (64 * NPAD) + idx];
    out[m * NOUT + o] = s;
}

extern "C" void kernel_launch(void* const* d_in, const int* in_sizes, int n_in,
                              void* d_out, int out_size, void* d_ws, size_t ws_size,
                              hipStream_t stream) {
    const float* tv  = (const float*)d_in[0];   // (64,3,64,64)
    const float* img = (const float*)d_in[1];   // (64,1024,1024,3)
    const float* w1  = (const float*)d_in[2];   // (48,4096)
    const float* b1  = (const float*)d_in[3];   // (4096,)
    const float* w2  = (const float*)d_in[4];   // (98304,1000)
    const float* b2  = (const float*)d_in[5];   // (1000,)
    float* out = (float*)d_out;                 // (64,1000) fp32

    char* ws = (char*)d_ws;
    float* xy = (float*)ws;                                         // 1 MiB
    unsigned short* A = (unsigned short*)(ws + (1u << 20));         // 12.58 MB
    float* part = (float*)(ws + (1u << 20) + (size_t)B_SZ * KGEMM * 2);  // 12.58 MB

    k_coords<<<B_SZ, 256, 0, stream>>>(tv, w1, b1, xy);
    k_patch<<<(B_SZ * N_PTS * 16) / 256, 256, 0, stream>>>(img, xy, A);
    k_gemm<<<dim3(16, NSPLIT), 256, 0, stream>>>(A, w2, part);
    k_reduce<<<(B_SZ * NPAD) / 256, 256, 0, stream>>>(part, b2, out);
}